// Round 4
// baseline (828.256 us; speedup 1.0000x reference)
//
#include <hip/hip_runtime.h>
#include <math.h>

// x: (8, 32, 64, 64, 64) fp32 ; weight: (32cin, 32cout, 3,3,3) ; bias,scale: (32,)
// pooled: (8, 32, 32, 32, 32) in d_ws ; S[256] after pooled in d_ws
// out: (8, 32, 64, 64, 64) fp32

constexpr int CIN_CHUNK = 8;

// ---------------- Pass 1: avg-pool 2x2x2 (+ zero the softmax sums) ----------------
// One thread = 4 pooled outputs along w' (float4 out). 8 float4 input loads.
__global__ void pool_kernel(const float* __restrict__ x, float* __restrict__ p,
                            float* __restrict__ S) {
    if (blockIdx.x == 0 && threadIdx.x < 256) S[threadIdx.x] = 0.f;
    int n = blockIdx.x * 256 + threadIdx.x;   // 0 .. 2^21-1
    int wg = n & 7;                            // w'-group (4 outputs)
    int h = (n >> 3) & 31;
    int d = (n >> 8) & 31;
    int bc = n >> 13;                          // b*32+c, 0..255
    const float* xb = x + (((size_t)(bc * 64 + 2 * d) * 64 + 2 * h) * 64 + 8 * wg);
    float4 a0 = *(const float4*)(xb);
    float4 a1 = *(const float4*)(xb + 4);
    float4 b0 = *(const float4*)(xb + 64);
    float4 b1 = *(const float4*)(xb + 68);
    float4 c0 = *(const float4*)(xb + 4096);
    float4 c1 = *(const float4*)(xb + 4100);
    float4 d0 = *(const float4*)(xb + 4160);
    float4 d1 = *(const float4*)(xb + 4164);
    float4 o;
    o.x = (a0.x + a0.y + b0.x + b0.y + c0.x + c0.y + d0.x + d0.y) * 0.125f;
    o.y = (a0.z + a0.w + b0.z + b0.w + c0.z + c0.w + d0.z + d0.w) * 0.125f;
    o.z = (a1.x + a1.y + b1.x + b1.y + c1.x + c1.y + d1.x + d1.y) * 0.125f;
    o.w = (a1.z + a1.w + b1.z + b1.w + c1.z + c1.w + d1.z + d1.w) * 0.125f;
    *(float4*)(p + (size_t)n * 4) = o;
}

// ---------------- Pass 2: conv-transpose + bias + clamp + exp + partial sums ------
// Block: (od', oh'-tile of 4, b). 512 threads = (cout 32) x (tg 16).
// tg: wb = (tg&7)*4 (w' segment of 4), R0 = (tg>>3)*2 (2 oh' rows).
// Each thread: acc[pd][ph][pw][rr][i] = 64 outputs.
__global__ __launch_bounds__(512, 4)
void convt_kernel(const float* __restrict__ P, const float* __restrict__ W,
                  const float* __restrict__ bias, float* __restrict__ out,
                  float* __restrict__ S) {
    __shared__ float Pl[CIN_CHUNK][2][5][36];  // [cin][plane][row][w(33 used)]
    __shared__ float Wl[CIN_CHUNK][32][28];    // [cin][cout][tap(27 used)], 16B-aligned rows

    const int odp = blockIdx.x;
    const int ohb = blockIdx.y * 4;
    const int b   = blockIdx.z;
    const int tid = threadIdx.x;
    const int cout = tid >> 4;
    const int tg   = tid & 15;
    const int wb = (tg & 7) * 4;
    const int R0 = (tg >> 3) * 2;

    float acc[2][2][2][2][4];
#pragma unroll
    for (int a0 = 0; a0 < 2; ++a0)
#pragma unroll
        for (int a1 = 0; a1 < 2; ++a1)
#pragma unroll
            for (int a2 = 0; a2 < 2; ++a2)
#pragma unroll
                for (int a3 = 0; a3 < 2; ++a3)
#pragma unroll
                    for (int a4 = 0; a4 < 4; ++a4) acc[a0][a1][a2][a3][a4] = 0.f;

    const float* pBase = &Pl[0][0][0][0] + R0 * 36 + wb;   // c=0, pl=0, j=0 row base

    for (int cc = 0; cc < 32; cc += CIN_CHUNK) {
        __syncthreads();
        // stage pooled tile: cin_chunk x 2 planes x 5 rows x 33 w, zero-padded
        for (int idx = tid; idx < CIN_CHUNK * 2 * 5 * 33; idx += 512) {
            int w = idx % 33;
            int t1 = idx / 33;
            int r = t1 % 5;
            int t2 = t1 / 5;
            int pl = t2 & 1;
            int c = t2 >> 1;
            int id = odp + pl;
            int ih = ohb + r;
            float v = 0.f;
            if (id < 32 && ih < 32 && w < 32)
                v = P[(((size_t)((b * 32 + cc + c) * 32) + id) * 32 + ih) * 32 + w];
            Pl[c][pl][r][w] = v;
        }
        // stage weights: src [cin][cout][27] contiguous -> dst stride 28 (16B-aligned)
        for (int idx = tid; idx < CIN_CHUNK * 32 * 27; idx += 512) {
            int q = idx / 27;
            int t = idx - q * 27;
            (&Wl[0][0][0])[q * 28 + t] = W[(size_t)cc * 864 + idx];
        }
        __syncthreads();

        for (int c = 0; c < CIN_CHUNK; ++c) {
            const float* pc = pBase + c * 360;
            const float4* wq = (const float4*)&Wl[c][cout][0];
            float pr[3][5];
            // ---- plane 1 (id = od'+1): taps kd==0 (t = 0..8) ----
#pragma unroll
            for (int j = 0; j < 3; ++j) {
                const float* rp = pc + 180 + j * 36;
                float4 v4 = *(const float4*)rp;
                pr[j][0] = v4.x; pr[j][1] = v4.y; pr[j][2] = v4.z; pr[j][3] = v4.w;
                pr[j][4] = rp[4];
            }
            {
                float4 qa = wq[0], qb = wq[1];
                float w8 = ((const float*)wq)[8];
                float wv[9] = {qa.x, qa.y, qa.z, qa.w, qb.x, qb.y, qb.z, qb.w, w8};
#pragma unroll
                for (int t = 0; t < 9; ++t) {
                    const int kh = t / 3, kw = t % 3;
                    const int ph = (kh == 1) ? 0 : 1, dh = (kh == 0) ? 1 : 0;
                    const int pw = (kw == 1) ? 0 : 1, dw = (kw == 0) ? 1 : 0;
                    float w0 = wv[t];
#pragma unroll
                    for (int rr = 0; rr < 2; ++rr)
#pragma unroll
                        for (int i = 0; i < 4; ++i)
                            acc[1][ph][pw][rr][i] += pr[rr + dh][i + dw] * w0;
                }
            }
            // ---- plane 0 (id = od'): taps kd==1 (pd=0), kd==2 (pd=1): t = 9..26 ----
#pragma unroll
            for (int j = 0; j < 3; ++j) {
                const float* rp = pc + j * 36;
                float4 v4 = *(const float4*)rp;
                pr[j][0] = v4.x; pr[j][1] = v4.y; pr[j][2] = v4.z; pr[j][3] = v4.w;
                pr[j][4] = rp[4];
            }
            {
                float4 q2 = wq[2], q3 = wq[3], q4 = wq[4], q5 = wq[5], q6 = wq[6];
                float wv[18] = {q2.y, q2.z, q2.w, q3.x, q3.y, q3.z, q3.w, q4.x, q4.y,
                                q4.z, q4.w, q5.x, q5.y, q5.z, q5.w, q6.x, q6.y, q6.z};
#pragma unroll
                for (int t = 9; t < 27; ++t) {
                    const int kd = t / 9, kh = (t / 3) % 3, kw = t % 3;
                    const int pd = (kd == 1) ? 0 : 1;
                    const int ph = (kh == 1) ? 0 : 1, dh = (kh == 0) ? 1 : 0;
                    const int pw = (kw == 1) ? 0 : 1, dw = (kw == 0) ? 1 : 0;
                    float w0 = wv[t - 9];
#pragma unroll
                    for (int rr = 0; rr < 2; ++rr)
#pragma unroll
                        for (int i = 0; i < 4; ++i)
                            acc[pd][ph][pw][rr][i] += pr[rr + dh][i + dw] * w0;
                }
            }
        }
    }

    // ---- epilogue: bias, clamp, exp, store, partial softmax sums ----
    const float bv = bias[cout];
    float lsum = 0.f;
    float* ob = out + ((size_t)(b * 32 + cout) * 262144);
#pragma unroll
    for (int pd = 0; pd < 2; ++pd) {
        const int od = 2 * odp + pd;
#pragma unroll
        for (int rr = 0; rr < 2; ++rr) {
#pragma unroll
            for (int ph = 0; ph < 2; ++ph) {
                const int oh = 2 * (ohb + R0 + rr) + ph;
                float v[8];
#pragma unroll
                for (int i = 0; i < 4; ++i)
#pragma unroll
                    for (int pw = 0; pw < 2; ++pw) {
                        float y = acc[pd][ph][pw][rr][i] + bv;
                        y = fminf(fmaxf(y, 0.f), 1.f);
                        float e = __expf(y);
                        lsum += e;
                        v[2 * i + pw] = e;
                    }
                float* dst = ob + (size_t)od * 4096 + oh * 64 + 2 * wb;
                *(float4*)dst = make_float4(v[0], v[1], v[2], v[3]);
                *(float4*)(dst + 4) = make_float4(v[4], v[5], v[6], v[7]);
            }
        }
    }
#pragma unroll
    for (int off = 1; off < 16; off <<= 1) lsum += __shfl_xor(lsum, off, 64);
    if (tg == 0) atomicAdd(&S[b * 32 + cout], lsum);
}

// ---------------- Pass 3: out *= scale[c] / S[b,c] --------------------------------
// grid (64, 256): blockIdx.y = (b,c); division hoisted to once per block.
__global__ void scale_kernel(float* __restrict__ out, const float* __restrict__ S,
                             const float* __restrict__ scale) {
    const int bc = blockIdx.y;
    const float m = scale[bc & 31] / S[bc];
    float4* p = (float4*)out + (size_t)bc * 65536 + blockIdx.x * 1024 + threadIdx.x;
#pragma unroll
    for (int k = 0; k < 4; ++k) {
        float4 v = p[k * 256];
        v.x *= m; v.y *= m; v.z *= m; v.w *= m;
        p[k * 256] = v;
    }
}

extern "C" void kernel_launch(void* const* d_in, const int* in_sizes, int n_in,
                              void* d_out, int out_size, void* d_ws, size_t ws_size,
                              hipStream_t stream) {
    const float* x     = (const float*)d_in[0];
    const float* W     = (const float*)d_in[1];
    const float* bias  = (const float*)d_in[2];
    const float* scale = (const float*)d_in[3];
    float* out = (float*)d_out;
    float* pooled = (float*)d_ws;                    // 32 MiB
    float* S = (float*)d_ws + 8 * 32 * 32768;        // 256 floats

    pool_kernel<<<8192, 256, 0, stream>>>(x, pooled, S);
    convt_kernel<<<dim3(32, 8, 8), 512, 0, stream>>>(pooled, W, bias, out, S);
    scale_kernel<<<dim3(64, 256), 256, 0, stream>>>(out, S, scale);
}